// Round 3
// baseline (165.755 us; speedup 1.0000x reference)
//
#include <hip/hip_runtime.h>
#include <math.h>

#define DIM 64
#define NNB 16
#define BATCH 16384

typedef float4 f4;

__device__ __forceinline__ float dot4(const f4 a, const f4 b) {
    return fmaf(a.x, b.x, fmaf(a.y, b.y, fmaf(a.z, b.z, a.w * b.w)));
}

// Sum across the 4 lane-groups (lanes differing in bits 4,5); chunk stays put.
__device__ __forceinline__ f4 xgrp_sum(f4 v) {
    v.x += __shfl_xor(v.x, 16, 64); v.y += __shfl_xor(v.y, 16, 64);
    v.z += __shfl_xor(v.z, 16, 64); v.w += __shfl_xor(v.w, 16, 64);
    v.x += __shfl_xor(v.x, 32, 64); v.y += __shfl_xor(v.y, 32, 64);
    v.z += __shfl_xor(v.z, 32, 64); v.w += __shfl_xor(v.w, 32, 64);
    return v;
}

// W chunk (d, s) lives at LDS slot d*16 + (s ^ ((d>>2)&15)).
// The XOR spreads the 4 lane-groups (whose d = 16g+j share j) across
// different bank offsets; without it all 64 lanes of a matvec step hit
// the same 8-bank set in the same order.
__device__ __forceinline__ int wslot(int d, int sIdx) {
    return d * 16 + (sIdx ^ ((d >> 2) & 15));
}

// EL=2 per wave. agg_W (16KB) and rel_emb (8KB, rows padded to 17 f4)
// are staged to LDS once per block: this deletes 24 of ~64 VMEM
// instructions per wave (all of them L1-hits that still cost TA
// address-processing). Remaining global traffic = compulsory gathers.
template <int WPB>
__global__ __launch_bounds__(WPB * 64, 4) void klgcn_kernel(
    const int* __restrict__ u, const int* __restrict__ v,
    const int* __restrict__ user_neighbor, const int* __restrict__ item_neighbor,
    const int* __restrict__ adj_ent, const int* __restrict__ adj_rel,
    const float* __restrict__ usr_emb, const float* __restrict__ ent_emb,
    const float* __restrict__ rel_emb, const float* __restrict__ agg_W,
    const float* __restrict__ agg_b, float* __restrict__ out)
{
    __shared__ f4 ldsW[1024];      // 16 KB, swizzled
    __shared__ f4 ldsRel[32 * 17]; // 8.7 KB, rows padded 16 -> 17 f4

    const int t = threadIdx.x;
    const int wave = t >> 6;
    const int lane = t & 63;
    const int g = lane >> 4;   // group 0..3: owns neighbor rows 4g..4g+3
    const int s = lane & 15;   // chunk 0..15: dims [4s, 4s+4)
    const int b0 = __builtin_amdgcn_readfirstlane((blockIdx.x * WPB + wave) * 2);
    const int bb[2] = {b0, b0 + 1};

    const f4* __restrict__ usr4 = (const f4*)usr_emb;
    const f4* __restrict__ ent4 = (const f4*)ent_emb;
    const f4* __restrict__ rel4 = (const f4*)rel_emb;
    const f4* __restrict__ W4   = (const f4*)agg_W;
    const f4* __restrict__ b4p  = (const f4*)agg_b;
    const int4* __restrict__ it4 = (const int4*)item_neighbor;
    const int4* __restrict__ un4 = (const int4*)user_neighbor;
    const int4* __restrict__ ar4 = (const int4*)adj_rel;
    const int4* __restrict__ ae4 = (const int4*)adj_ent;

    // ---- Uniform scalars for both elements (s_load path).
    int ub[2], vb[2];
#pragma unroll
    for (int el = 0; el < 2; el++) {
        ub[el] = __builtin_amdgcn_readfirstlane(u[bb[el]]);
        vb[el] = __builtin_amdgcn_readfirstlane(v[bb[el]]);
    }

    // ---- Per-lane contiguous index loads: one int4 per table per element.
    int4 iit[2], iun[2], iar[2], iae[2];
#pragma unroll
    for (int el = 0; el < 2; el++) {
        iit[el] = it4[bb[el] * 4 + g];
        iun[el] = un4[bb[el] * 4 + g];
        iar[el] = ar4[vb[el] * 4 + g];
        iae[el] = ae4[vb[el] * 4 + g];
    }

    // ---- Direct rows.
    f4 ue4[2], ie4[2];
#pragma unroll
    for (int el = 0; el < 2; el++) {
        ue4[el] = usr4[(long)ub[el] * 16 + s];
        ie4[el] = ent4[(long)vb[el] * 16 + s];
    }

    // ---- Stage W (swizzled) and rel (row-padded) into LDS: 6 coalesced
    // loads per thread, once per block.
#pragma unroll
    for (int k = 0; k < 4; k++) {
        const int c = t + 256 * k;
        ldsW[wslot(c >> 4, c & 15)] = W4[c];
    }
#pragma unroll
    for (int k = 0; k < 2; k++) {
        const int c = t + 256 * k;
        ldsRel[(c >> 4) * 17 + (c & 15)] = rel4[c];
    }
    // Barrier drain here only covers the cheap idx/direct loads above,
    // so register pressure across it stays low.
    __syncthreads();

    // ---- Compulsory row gathers (HBM): Ag, Lu, Li. 24 instr per wave.
    f4 Ag[2][4], Lu[2][4], Li[2][4];
#pragma unroll
    for (int el = 0; el < 2; el++) {
        Ag[el][0] = ent4[(long)iae[el].x * 16 + s];
        Ag[el][1] = ent4[(long)iae[el].y * 16 + s];
        Ag[el][2] = ent4[(long)iae[el].z * 16 + s];
        Ag[el][3] = ent4[(long)iae[el].w * 16 + s];
    }
#pragma unroll
    for (int el = 0; el < 2; el++) {
        Lu[el][0] = usr4[(long)iit[el].x * 16 + s];
        Lu[el][1] = usr4[(long)iit[el].y * 16 + s];
        Lu[el][2] = usr4[(long)iit[el].z * 16 + s];
        Lu[el][3] = usr4[(long)iit[el].w * 16 + s];
    }
#pragma unroll
    for (int el = 0; el < 2; el++) {
        Li[el][0] = ent4[(long)iun[el].x * 16 + s];
        Li[el][1] = ent4[(long)iun[el].y * 16 + s];
        Li[el][2] = ent4[(long)iun[el].z * 16 + s];
        Li[el][3] = ent4[(long)iun[el].w * 16 + s];
    }

    // ---- Attention scores; Re rows now come from LDS (no TA cost).
    float e[2][4], inv[2];
#pragma unroll
    for (int el = 0; el < 2; el++) {
        const int rid[4] = {iar[el].x, iar[el].y, iar[el].z, iar[el].w};
        float sc[4];
#pragma unroll
        for (int k = 0; k < 4; k++) {
            const f4 re = ldsRel[rid[k] * 17 + s];
            float p = dot4(ue4[el], re);
            p += __shfl_xor(p, 1, 64); p += __shfl_xor(p, 2, 64);
            p += __shfl_xor(p, 4, 64); p += __shfl_xor(p, 8, 64);
            sc[k] = p;
        }
        float m = fmaxf(fmaxf(sc[0], sc[1]), fmaxf(sc[2], sc[3]));
        m = fmaxf(m, __shfl_xor(m, 16, 64));
        m = fmaxf(m, __shfl_xor(m, 32, 64));
        float ssum = 0.f;
#pragma unroll
        for (int k = 0; k < 4; k++) { e[el][k] = __expf(sc[k] - m); ssum += e[el][k]; }
        ssum += __shfl_xor(ssum, 16, 64);
        ssum += __shfl_xor(ssum, 32, 64);
        inv[el] = 1.0f / ssum;
    }

    // ---- neighbors_agg + combined.
    float cc[2][4];
#pragma unroll
    for (int el = 0; el < 2; el++) {
        f4 ag = {0.f, 0.f, 0.f, 0.f};
#pragma unroll
        for (int k = 0; k < 4; k++) {
            ag.x = fmaf(e[el][k], Ag[el][k].x, ag.x);
            ag.y = fmaf(e[el][k], Ag[el][k].y, ag.y);
            ag.z = fmaf(e[el][k], Ag[el][k].z, ag.z);
            ag.w = fmaf(e[el][k], Ag[el][k].w, ag.w);
        }
        ag = xgrp_sum(ag);  // sum over all 16 rows; replicated across groups
        cc[el][0] = fmaf(ag.x, inv[el], ie4[el].x);
        cc[el][1] = fmaf(ag.y, inv[el], ie4[el].y);
        cc[el][2] = fmaf(ag.z, inv[el], ie4[el].z);
        cc[el][3] = fmaf(ag.w, inv[el], ie4[el].w);
    }

    // ---- lite sums.
    f4 lu[2], li[2];
#pragma unroll
    for (int el = 0; el < 2; el++) {
        f4 tt;
        tt.x = Lu[el][0].x + Lu[el][1].x + Lu[el][2].x + Lu[el][3].x;
        tt.y = Lu[el][0].y + Lu[el][1].y + Lu[el][2].y + Lu[el][3].y;
        tt.z = Lu[el][0].z + Lu[el][1].z + Lu[el][2].z + Lu[el][3].z;
        tt.w = Lu[el][0].w + Lu[el][1].w + Lu[el][2].w + Lu[el][3].w;
        lu[el] = xgrp_sum(tt);
        tt.x = Li[el][0].x + Li[el][1].x + Li[el][2].x + Li[el][3].x;
        tt.y = Li[el][0].y + Li[el][1].y + Li[el][2].y + Li[el][3].y;
        tt.z = Li[el][0].z + Li[el][1].z + Li[el][2].z + Li[el][3].z;
        tt.w = Li[el][0].w + Li[el][1].w + Li[el][2].w + Li[el][3].w;
        li[el] = xgrp_sum(tt);
    }

    // ---- 64x64 matvec from LDS: one ds_read per j serves BOTH elements.
    // comb replicated across groups; chunk 4g+(j>>2) lives in lane 20g+(j>>2).
    f4 acc[2] = {{0.f, 0.f, 0.f, 0.f}, {0.f, 0.f, 0.f, 0.f}};
#pragma unroll
    for (int j = 0; j < 16; j++) {
        const int d = 16 * g + j;
        const f4 w = ldsW[wslot(d, s)];
        const int src = 20 * g + (j >> 2);
#pragma unroll
        for (int el = 0; el < 2; el++) {
            const float cd = __shfl(cc[el][j & 3], src, 64);
            acc[el].x = fmaf(cd, w.x, acc[el].x);
            acc[el].y = fmaf(cd, w.y, acc[el].y);
            acc[el].z = fmaf(cd, w.z, acc[el].z);
            acc[el].w = fmaf(cd, w.w, acc[el].w);
        }
    }
    const f4 bias = b4p[s];
    float res[2];
#pragma unroll
    for (int el = 0; el < 2; el++) {
        acc[el] = xgrp_sum(acc[el]);
        f4 item4;
        item4.x = tanhf(acc[el].x + bias.x);
        item4.y = tanhf(acc[el].y + bias.y);
        item4.z = tanhf(acc[el].z + bias.z);
        item4.w = tanhf(acc[el].w + bias.w);

        f4 uf, itf;
        uf.x = 0.5f * fmaf(lu[el].x, 1.f / NNB, ue4[el].x);
        uf.y = 0.5f * fmaf(lu[el].y, 1.f / NNB, ue4[el].y);
        uf.z = 0.5f * fmaf(lu[el].z, 1.f / NNB, ue4[el].z);
        uf.w = 0.5f * fmaf(lu[el].w, 1.f / NNB, ue4[el].w);
        itf.x = 0.5f * fmaf(li[el].x, 1.f / NNB, item4.x);
        itf.y = 0.5f * fmaf(li[el].y, 1.f / NNB, item4.y);
        itf.z = 0.5f * fmaf(li[el].z, 1.f / NNB, item4.z);
        itf.w = 0.5f * fmaf(li[el].w, 1.f / NNB, item4.w);

        float p = dot4(uf, itf);
        p += __shfl_xor(p, 1, 64); p += __shfl_xor(p, 2, 64);
        p += __shfl_xor(p, 4, 64); p += __shfl_xor(p, 8, 64);
        res[el] = 1.0f / (1.0f + __expf(-p));
    }

    if (lane == 0) {
        // b0 is even -> 8B-aligned float2 store.
        *(float2*)(out + b0) = make_float2(res[0], res[1]);
    }
}

extern "C" void kernel_launch(void* const* d_in, const int* in_sizes, int n_in,
                              void* d_out, int out_size, void* d_ws, size_t ws_size,
                              hipStream_t stream)
{
    const int*   u             = (const int*)d_in[0];
    const int*   v             = (const int*)d_in[1];
    const int*   user_neighbor = (const int*)d_in[2];
    const int*   item_neighbor = (const int*)d_in[3];
    const int*   adj_ent       = (const int*)d_in[4];
    const int*   adj_rel       = (const int*)d_in[5];
    const float* usr_emb       = (const float*)d_in[6];
    const float* ent_emb       = (const float*)d_in[7];
    const float* rel_emb       = (const float*)d_in[8];
    const float* agg_W         = (const float*)d_in[9];
    const float* agg_b         = (const float*)d_in[10];
    float* out = (float*)d_out;

    constexpr int WPB = 4;  // 4 waves/block, TWO batch elements per wave
    dim3 grid(BATCH / (WPB * 2)), block(WPB * 64);
    klgcn_kernel<WPB><<<grid, block, 0, stream>>>(
        u, v, user_neighbor, item_neighbor, adj_ent, adj_rel,
        usr_emb, ent_emb, rel_emb, agg_W, agg_b, out);
}

// Round 4
// 152.092 us; speedup vs baseline: 1.0898x; 1.0898x over previous
//
#include <hip/hip_runtime.h>
#include <math.h>

#define DIM 64
#define NNB 16
#define BATCH 16384

typedef float4 f4;

__device__ __forceinline__ float dot4(const f4 a, const f4 b) {
    return fmaf(a.x, b.x, fmaf(a.y, b.y, fmaf(a.z, b.z, a.w * b.w)));
}

// Sum across the 4 lane-groups (lanes differing in bits 4,5); chunk stays put.
__device__ __forceinline__ f4 xgrp_sum(f4 v) {
    v.x += __shfl_xor(v.x, 16, 64); v.y += __shfl_xor(v.y, 16, 64);
    v.z += __shfl_xor(v.z, 16, 64); v.w += __shfl_xor(v.w, 16, 64);
    v.x += __shfl_xor(v.x, 32, 64); v.y += __shfl_xor(v.y, 32, 64);
    v.z += __shfl_xor(v.z, 32, 64); v.w += __shfl_xor(v.w, 32, 64);
    return v;
}

// EL=2 per wave. agg_W (16KB) and rel_emb (8KB, rows padded 16->17 f4) are
// staged to LDS once per block, FIRST, so the __syncthreads drain covers only
// 6 uniform coalesced loads. This deletes 24 of ~62 VMEM instructions per
// wave (all cache-hitting ones; HBM miss traffic unchanged) — the clean test
// of the TA/address-throughput theory. launch_bounds min-waves=3 keeps the
// VGPR cap at ~170 (baseline regime, VGPR=76, no spill); dropping the Re
// register array lowers peak pressure vs baseline.
template <int WPB>
__global__ __launch_bounds__(WPB * 64, 3) void klgcn_kernel(
    const int* __restrict__ u, const int* __restrict__ v,
    const int* __restrict__ user_neighbor, const int* __restrict__ item_neighbor,
    const int* __restrict__ adj_ent, const int* __restrict__ adj_rel,
    const float* __restrict__ usr_emb, const float* __restrict__ ent_emb,
    const float* __restrict__ rel_emb, const float* __restrict__ agg_W,
    const float* __restrict__ agg_b, float* __restrict__ out)
{
    __shared__ f4 ldsW[1024];      // 16 KB, plain [d][s] layout
    __shared__ f4 ldsRel[32 * 17]; // 8.7 KB, rows padded 16 -> 17 f4

    const int t = threadIdx.x;
    const int wave = t >> 6;
    const int lane = t & 63;
    const int g = lane >> 4;   // group 0..3: owns neighbor rows 4g..4g+3
    const int s = lane & 15;   // chunk 0..15: dims [4s, 4s+4)
    const int b0 = __builtin_amdgcn_readfirstlane((blockIdx.x * WPB + wave) * 2);
    const int bb[2] = {b0, b0 + 1};

    const f4* __restrict__ usr4 = (const f4*)usr_emb;
    const f4* __restrict__ ent4 = (const f4*)ent_emb;
    const f4* __restrict__ rel4 = (const f4*)rel_emb;
    const f4* __restrict__ W4   = (const f4*)agg_W;
    const f4* __restrict__ b4p  = (const f4*)agg_b;
    const int4* __restrict__ it4 = (const int4*)item_neighbor;
    const int4* __restrict__ un4 = (const int4*)user_neighbor;
    const int4* __restrict__ ar4 = (const int4*)adj_rel;
    const int4* __restrict__ ae4 = (const int4*)adj_ent;

    // ---- Stage W and rel into LDS: 6 coalesced loads/thread, once per block.
#pragma unroll
    for (int k = 0; k < 4; k++) {
        const int c = t + 256 * k;
        ldsW[c] = W4[c];
    }
#pragma unroll
    for (int k = 0; k < 2; k++) {
        const int c = t + 256 * k;
        ldsRel[(c >> 4) * 17 + (c & 15)] = rel4[c];
    }
    __syncthreads();  // drains only the 6 staging loads

    // ---- Uniform scalars for both elements (s_load path).
    int ub[2], vb[2];
#pragma unroll
    for (int el = 0; el < 2; el++) {
        ub[el] = __builtin_amdgcn_readfirstlane(u[bb[el]]);
        vb[el] = __builtin_amdgcn_readfirstlane(v[bb[el]]);
    }

    // ---- Per-lane contiguous index loads: one int4 per table per element.
    int4 iit[2], iun[2], iar[2], iae[2];
#pragma unroll
    for (int el = 0; el < 2; el++) {
        iit[el] = it4[bb[el] * 4 + g];
        iun[el] = un4[bb[el] * 4 + g];
        iar[el] = ar4[vb[el] * 4 + g];
        iae[el] = ae4[vb[el] * 4 + g];
    }

    // ---- Direct rows.
    f4 ue4[2], ie4[2];
#pragma unroll
    for (int el = 0; el < 2; el++) {
        ue4[el] = usr4[(long)ub[el] * 16 + s];
        ie4[el] = ent4[(long)vb[el] * 16 + s];
    }

    // ---- Compulsory row gathers (HBM): Ag, Lu, Li. 24 instr per wave.
    f4 Ag[2][4], Lu[2][4], Li[2][4];
#pragma unroll
    for (int el = 0; el < 2; el++) {
        Ag[el][0] = ent4[(long)iae[el].x * 16 + s];
        Ag[el][1] = ent4[(long)iae[el].y * 16 + s];
        Ag[el][2] = ent4[(long)iae[el].z * 16 + s];
        Ag[el][3] = ent4[(long)iae[el].w * 16 + s];
    }
#pragma unroll
    for (int el = 0; el < 2; el++) {
        Lu[el][0] = usr4[(long)iit[el].x * 16 + s];
        Lu[el][1] = usr4[(long)iit[el].y * 16 + s];
        Lu[el][2] = usr4[(long)iit[el].z * 16 + s];
        Lu[el][3] = usr4[(long)iit[el].w * 16 + s];
    }
#pragma unroll
    for (int el = 0; el < 2; el++) {
        Li[el][0] = ent4[(long)iun[el].x * 16 + s];
        Li[el][1] = ent4[(long)iun[el].y * 16 + s];
        Li[el][2] = ent4[(long)iun[el].z * 16 + s];
        Li[el][3] = ent4[(long)iun[el].w * 16 + s];
    }

    // ---- Attention scores; Re rows come from LDS (no VMEM instr, no regs).
    float e[2][4], inv[2];
#pragma unroll
    for (int el = 0; el < 2; el++) {
        const int rid[4] = {iar[el].x, iar[el].y, iar[el].z, iar[el].w};
        float sc[4];
#pragma unroll
        for (int k = 0; k < 4; k++) {
            const f4 re = ldsRel[rid[k] * 17 + s];
            float p = dot4(ue4[el], re);
            p += __shfl_xor(p, 1, 64); p += __shfl_xor(p, 2, 64);
            p += __shfl_xor(p, 4, 64); p += __shfl_xor(p, 8, 64);
            sc[k] = p;
        }
        float m = fmaxf(fmaxf(sc[0], sc[1]), fmaxf(sc[2], sc[3]));
        m = fmaxf(m, __shfl_xor(m, 16, 64));
        m = fmaxf(m, __shfl_xor(m, 32, 64));
        float ssum = 0.f;
#pragma unroll
        for (int k = 0; k < 4; k++) { e[el][k] = __expf(sc[k] - m); ssum += e[el][k]; }
        ssum += __shfl_xor(ssum, 16, 64);
        ssum += __shfl_xor(ssum, 32, 64);
        inv[el] = 1.0f / ssum;
    }

    // ---- neighbors_agg + combined.
    float cc[2][4];
#pragma unroll
    for (int el = 0; el < 2; el++) {
        f4 ag = {0.f, 0.f, 0.f, 0.f};
#pragma unroll
        for (int k = 0; k < 4; k++) {
            ag.x = fmaf(e[el][k], Ag[el][k].x, ag.x);
            ag.y = fmaf(e[el][k], Ag[el][k].y, ag.y);
            ag.z = fmaf(e[el][k], Ag[el][k].z, ag.z);
            ag.w = fmaf(e[el][k], Ag[el][k].w, ag.w);
        }
        ag = xgrp_sum(ag);  // sum over all 16 rows; replicated across groups
        cc[el][0] = fmaf(ag.x, inv[el], ie4[el].x);
        cc[el][1] = fmaf(ag.y, inv[el], ie4[el].y);
        cc[el][2] = fmaf(ag.z, inv[el], ie4[el].z);
        cc[el][3] = fmaf(ag.w, inv[el], ie4[el].w);
    }

    // ---- lite sums.
    f4 lu[2], li[2];
#pragma unroll
    for (int el = 0; el < 2; el++) {
        f4 tt;
        tt.x = Lu[el][0].x + Lu[el][1].x + Lu[el][2].x + Lu[el][3].x;
        tt.y = Lu[el][0].y + Lu[el][1].y + Lu[el][2].y + Lu[el][3].y;
        tt.z = Lu[el][0].z + Lu[el][1].z + Lu[el][2].z + Lu[el][3].z;
        tt.w = Lu[el][0].w + Lu[el][1].w + Lu[el][2].w + Lu[el][3].w;
        lu[el] = xgrp_sum(tt);
        tt.x = Li[el][0].x + Li[el][1].x + Li[el][2].x + Li[el][3].x;
        tt.y = Li[el][0].y + Li[el][1].y + Li[el][2].y + Li[el][3].y;
        tt.z = Li[el][0].z + Li[el][1].z + Li[el][2].z + Li[el][3].z;
        tt.w = Li[el][0].w + Li[el][1].w + Li[el][2].w + Li[el][3].w;
        li[el] = xgrp_sum(tt);
    }

    // ---- 64x64 matvec from LDS: one ds_read per j serves BOTH elements.
    // comb replicated across groups; chunk 4g+(j>>2) lives in lane 20g+(j>>2).
    f4 acc[2] = {{0.f, 0.f, 0.f, 0.f}, {0.f, 0.f, 0.f, 0.f}};
#pragma unroll
    for (int j = 0; j < 16; j++) {
        const int d = 16 * g + j;
        const f4 w = ldsW[d * 16 + s];
        const int src = 20 * g + (j >> 2);
#pragma unroll
        for (int el = 0; el < 2; el++) {
            const float cd = __shfl(cc[el][j & 3], src, 64);
            acc[el].x = fmaf(cd, w.x, acc[el].x);
            acc[el].y = fmaf(cd, w.y, acc[el].y);
            acc[el].z = fmaf(cd, w.z, acc[el].z);
            acc[el].w = fmaf(cd, w.w, acc[el].w);
        }
    }
    const f4 bias = b4p[s];
    float res[2];
#pragma unroll
    for (int el = 0; el < 2; el++) {
        acc[el] = xgrp_sum(acc[el]);
        f4 item4;
        item4.x = tanhf(acc[el].x + bias.x);
        item4.y = tanhf(acc[el].y + bias.y);
        item4.z = tanhf(acc[el].z + bias.z);
        item4.w = tanhf(acc[el].w + bias.w);

        f4 uf, itf;
        uf.x = 0.5f * fmaf(lu[el].x, 1.f / NNB, ue4[el].x);
        uf.y = 0.5f * fmaf(lu[el].y, 1.f / NNB, ue4[el].y);
        uf.z = 0.5f * fmaf(lu[el].z, 1.f / NNB, ue4[el].z);
        uf.w = 0.5f * fmaf(lu[el].w, 1.f / NNB, ue4[el].w);
        itf.x = 0.5f * fmaf(li[el].x, 1.f / NNB, item4.x);
        itf.y = 0.5f * fmaf(li[el].y, 1.f / NNB, item4.y);
        itf.z = 0.5f * fmaf(li[el].z, 1.f / NNB, item4.z);
        itf.w = 0.5f * fmaf(li[el].w, 1.f / NNB, item4.w);

        float p = dot4(uf, itf);
        p += __shfl_xor(p, 1, 64); p += __shfl_xor(p, 2, 64);
        p += __shfl_xor(p, 4, 64); p += __shfl_xor(p, 8, 64);
        res[el] = 1.0f / (1.0f + __expf(-p));
    }

    if (lane == 0) {
        // b0 is even -> 8B-aligned float2 store.
        *(float2*)(out + b0) = make_float2(res[0], res[1]);
    }
}

extern "C" void kernel_launch(void* const* d_in, const int* in_sizes, int n_in,
                              void* d_out, int out_size, void* d_ws, size_t ws_size,
                              hipStream_t stream)
{
    const int*   u             = (const int*)d_in[0];
    const int*   v             = (const int*)d_in[1];
    const int*   user_neighbor = (const int*)d_in[2];
    const int*   item_neighbor = (const int*)d_in[3];
    const int*   adj_ent       = (const int*)d_in[4];
    const int*   adj_rel       = (const int*)d_in[5];
    const float* usr_emb       = (const float*)d_in[6];
    const float* ent_emb       = (const float*)d_in[7];
    const float* rel_emb       = (const float*)d_in[8];
    const float* agg_W         = (const float*)d_in[9];
    const float* agg_b         = (const float*)d_in[10];
    float* out = (float*)d_out;

    constexpr int WPB = 4;  // 4 waves/block, TWO batch elements per wave
    dim3 grid(BATCH / (WPB * 2)), block(WPB * 64);
    klgcn_kernel<WPB><<<grid, block, 0, stream>>>(
        u, v, user_neighbor, item_neighbor, adj_ent, adj_rel,
        usr_emb, ent_emb, rel_emb, agg_W, agg_b, out);
}